// Round 17
// baseline (394.188 us; speedup 1.0000x reference)
//
#include <hip/hip_runtime.h>
#include <hip/hip_bf16.h>
#include <cstdint>
#include <cstddef>

#define NN 50000
#define NE 600000
#define NG 2000
#define NBUCK 49          // ceil(50000 / 1024)
#define SLOTS 16
#define NCHUNK 3125       // 50000 / 16 exactly

typedef __attribute__((ext_vector_type(8))) short bf8;
typedef __attribute__((ext_vector_type(4))) float f32x4;

__device__ __forceinline__ unsigned short f2bf(float f) {
    uint32_t u = __float_as_uint(f);
    uint32_t r = (u + 0x7FFFu + ((u >> 16) & 1u)) >> 16;
    return (unsigned short)r;
}
__device__ __forceinline__ float bf2f(unsigned short h) {
    return __uint_as_float(((uint32_t)h) << 16);
}

// ---------------- fp32 -> bf16 conversion (x inputs) ----------------
__global__ __launch_bounds__(256) void conv_bf16_kernel(const float* __restrict__ x0,
                                                        const float* __restrict__ x1,
                                                        unsigned short* __restrict__ out) {
    int b = blockIdx.y;
    const float* x = b ? x1 : x0;
    unsigned short* o = out + (size_t)b * NN * 64;
    int i = (blockIdx.x * 256 + threadIdx.x) * 4;
    if (i + 3 < NN * 64) {
        float4 v = *(const float4*)&x[i];
        ushort4 r = make_ushort4(f2bf(v.x), f2bf(v.y), f2bf(v.z), f2bf(v.w));
        *(ushort4*)&o[i] = r;
    }
}

// ---------------- W pack: [K][N] fp32 -> MFMA B-frag-contiguous bf16 ----------------
template<int K, int N>
__global__ __launch_bounds__(256) void pack_w(const float* __restrict__ W0,
                                              const float* __restrict__ W1,
                                              unsigned short* __restrict__ out) {
    int b = blockIdx.y;
    const float* W = b ? W1 : W0;
    unsigned short* o = out + (size_t)b * K * N;
    int idx = blockIdx.x * 256 + threadIdx.x;
    const int total = (N / 16) * (K / 32) * 64;
    if (idx >= total) return;
    int l = idx & 63;
    int th = idx >> 6;
    int h = th % (K / 32);
    int t = th / (K / 32);
    int col = t * 16 + (l & 15);
    int k0 = h * 32 + (l >> 4) * 8;
    ushort4 lo = make_ushort4(f2bf(W[(k0 + 0) * N + col]), f2bf(W[(k0 + 1) * N + col]),
                              f2bf(W[(k0 + 2) * N + col]), f2bf(W[(k0 + 3) * N + col]));
    ushort4 hi = make_ushort4(f2bf(W[(k0 + 4) * N + col]), f2bf(W[(k0 + 5) * N + col]),
                              f2bf(W[(k0 + 6) * N + col]), f2bf(W[(k0 + 7) * N + col]));
    *(ushort4*)&o[idx * 8] = lo;
    *(ushort4*)&o[idx * 8 + 4] = hi;
}

// ---------------- Bucketed CSR build ----------------
__global__ __launch_bounds__(256) void bucket_hist(const int* __restrict__ d0,
                                                   const int* __restrict__ d1,
                                                   int* __restrict__ bucketCnt, int nE) {
    int b = blockIdx.y;
    const int* dst = b ? d1 : d0;
    __shared__ int h[NBUCK];
    for (int i = threadIdx.x; i < NBUCK; i += 256) h[i] = 0;
    __syncthreads();
    for (int e = blockIdx.x * 256 + threadIdx.x; e < nE; e += gridDim.x * 256)
        atomicAdd(&h[dst[e] >> 10], 1);
    __syncthreads();
    for (int i = threadIdx.x; i < NBUCK; i += 256)
        if (h[i]) atomicAdd(&bucketCnt[b * NBUCK + i], h[i]);
}

__global__ void bucket_scan(const int* __restrict__ bucketCnt,
                            int* __restrict__ bucketOff, int* __restrict__ bucketCur) {
    int b = threadIdx.x;
    if (b < 2) {
        int run = 0;
        for (int i = 0; i < NBUCK; ++i) {
            bucketOff[b * NBUCK + i] = run;
            bucketCur[b * NBUCK + i] = run;
            run += bucketCnt[b * NBUCK + i];
        }
    }
}

__global__ __launch_bounds__(256) void bucket_scatter(const int* __restrict__ s0,
                                                      const int* __restrict__ d0,
                                                      const int* __restrict__ s1,
                                                      const int* __restrict__ d1,
                                                      int* __restrict__ bucketCur,
                                                      uint32_t* __restrict__ bent, int nE) {
    int b = blockIdx.y;
    const int* src = b ? s1 : s0;
    const int* dst = b ? d1 : d0;
    __shared__ int cnt[NBUCK];
    __shared__ int base[NBUCK];
    const int tid = threadIdx.x;
    for (int i = tid; i < NBUCK; i += 256) cnt[i] = 0;
    __syncthreads();

    const int e0 = blockIdx.x * 2048 + tid;
    int bk[8], slot[8];
    uint32_t pay[8];
#pragma unroll
    for (int k = 0; k < 8; ++k) {
        int e = e0 + k * 256;
        if (e < nE) {
            int d = dst[e], s = src[e];
            bk[k] = d >> 10;
            pay[k] = ((uint32_t)(d & 1023) << 16) | (uint32_t)s;
            slot[k] = atomicAdd(&cnt[bk[k]], 1);
        } else bk[k] = -1;
    }
    __syncthreads();
    for (int i = tid; i < NBUCK; i += 256) {
        int c = cnt[i];
        base[i] = c ? atomicAdd(&bucketCur[b * NBUCK + i], c) : 0;
    }
    __syncthreads();
#pragma unroll
    for (int k = 0; k < 8; ++k)
        if (bk[k] >= 0)
            bent[(size_t)b * NE + base[bk[k]] + slot[k]] = pay[k];
}

__global__ __launch_bounds__(256) void csr_build(const uint32_t* __restrict__ bent,
                                                 const int* __restrict__ bucketOff,
                                                 const int* __restrict__ bucketCnt,
                                                 int* __restrict__ row_ptr,
                                                 float* __restrict__ dinv,
                                                 uint16_t* __restrict__ perm) {
    __shared__ int lcnt[1024];
    __shared__ int lcur[1024];
    __shared__ int sscan[256];
    const int bk = blockIdx.x;
    const int b = blockIdx.y;
    const int tid = threadIdx.x;
    const int ebase = bucketOff[b * NBUCK + bk];
    const int ecnt = bucketCnt[b * NBUCK + bk];
    const int node0 = bk << 10;
    const uint32_t* be = bent + (size_t)b * NE + ebase;
    int* rp = row_ptr + b * (NN + 1);
    float* dv = dinv + (size_t)b * NN;
    uint16_t* pm = perm + (size_t)b * NE + ebase;

    for (int i = tid; i < 1024; i += 256) lcnt[i] = 0;
    __syncthreads();
    for (int i = tid; i < ecnt; i += 256) atomicAdd(&lcnt[be[i] >> 16], 1);
    __syncthreads();

    int c[4], s = 0;
#pragma unroll
    for (int j = 0; j < 4; ++j) { c[j] = lcnt[tid * 4 + j]; s += c[j]; }
    sscan[tid] = s;
    __syncthreads();
    for (int off = 1; off < 256; off <<= 1) {
        int v = (tid >= off) ? sscan[tid - off] : 0;
        __syncthreads();
        sscan[tid] += v;
        __syncthreads();
    }
    int run = sscan[tid] - s;
#pragma unroll
    for (int j = 0; j < 4; ++j) {
        int nl = tid * 4 + j;
        int g = node0 + nl;
        if (g < NN) {
            rp[g] = ebase + run;
            lcur[nl] = run;
            dv[g] = rsqrtf((float)c[j] + 1.0f);
        }
        run += c[j];
    }
    if (bk == NBUCK - 1 && tid == 0) rp[NN] = ebase + ecnt;
    __syncthreads();

    for (int i = tid; i < ecnt; i += 256) {
        uint32_t en = be[i];
        int nl = en >> 16;
        int pos = atomicAdd(&lcur[nl], 1);
        pm[pos] = (uint16_t)(en & 0xFFFFu);
    }
}

__global__ __launch_bounds__(256) void weight_fill(const uint16_t* __restrict__ perm,
                                                   const float* __restrict__ dinv,
                                                   uint32_t* __restrict__ permw, int nE) {
    int b = blockIdx.y;
    const uint16_t* pm = perm + (size_t)b * NE;
    const float* dv = dinv + (size_t)b * NN;
    uint32_t* pw = permw + (size_t)b * NE;
    int i = (blockIdx.x * 256 + threadIdx.x) * 4;
    if (i + 3 < nE) {
        ushort4 s4 = *(const ushort4*)&pm[i];
        uint4 o;
        o.x = ((uint32_t)f2bf(dv[s4.x]) << 16) | (uint32_t)s4.x;
        o.y = ((uint32_t)f2bf(dv[s4.y]) << 16) | (uint32_t)s4.y;
        o.z = ((uint32_t)f2bf(dv[s4.z]) << 16) | (uint32_t)s4.z;
        o.w = ((uint32_t)f2bf(dv[s4.w]) << 16) | (uint32_t)s4.w;
        *(uint4*)&pw[i] = o;
    } else {
        for (; i < nE; ++i) {
            uint16_t s = pm[i];
            pw[i] = ((uint32_t)f2bf(dv[s]) << 16) | (uint32_t)s;
        }
    }
}

// ---------------- GEMM1 (MFMA): Ybf16[n,128] = Xbf16[n,64] @ W[64,128] ----------------
template<bool STATS>
__global__ __launch_bounds__(256) void gemm1_mfma(const unsigned short* __restrict__ Xbf,
                                                  const unsigned short* __restrict__ Wp,
                                                  unsigned short* __restrict__ Y,
                                                  float* __restrict__ sums) {
    __shared__ float ls[128], ls2[128];
    const int b = blockIdx.y;
    const unsigned short* __restrict__ X = Xbf + (size_t)b * NN * 64;
    const unsigned short* __restrict__ W = Wp + (size_t)b * 64 * 128;
    unsigned short* __restrict__ Yb = Y + (size_t)b * NN * 128;
    const int tid = threadIdx.x;
    const int w = tid >> 6, lane = tid & 63;
    if (STATS) {
        for (int i = tid; i < 128; i += 256) { ls[i] = 0.f; ls2[i] = 0.f; }
        __syncthreads();
    }
    const int chunk = blockIdx.x * 4 + w;
    const bool act = chunk < NCHUNK;
    const int m = lane & 15, quad = lane >> 4;

    if (act) {
        const int row = chunk * 16 + m;
        bf8 a0 = *(const bf8*)&X[(size_t)row * 64 + quad * 8];
        bf8 a1 = *(const bf8*)&X[(size_t)row * 64 + 32 + quad * 8];
        f32x4 acc[8];
#pragma unroll
        for (int t = 0; t < 8; ++t) acc[t] = (f32x4){0.f, 0.f, 0.f, 0.f};
#pragma unroll
        for (int t = 0; t < 8; ++t) {
            bf8 b0 = *(const bf8*)&W[((t * 2 + 0) * 64 + lane) * 8];
            bf8 b1 = *(const bf8*)&W[((t * 2 + 1) * 64 + lane) * 8];
            acc[t] = __builtin_amdgcn_mfma_f32_16x16x32_bf16(a0, b0, acc[t], 0, 0, 0);
            acc[t] = __builtin_amdgcn_mfma_f32_16x16x32_bf16(a1, b1, acc[t], 0, 0, 0);
        }
        const int rbase = chunk * 16 + quad * 4;
#pragma unroll
        for (int t = 0; t < 8; ++t) {
            float s = 0.f, s2 = 0.f;
#pragma unroll
            for (int r = 0; r < 4; ++r) {
                float v = acc[t][r];
                Yb[(size_t)(rbase + r) * 128 + t * 16 + m] = f2bf(v);
                s += v; s2 = fmaf(v, v, s2);
            }
            if (STATS) {
                atomicAdd(&ls[t * 16 + m], s);
                atomicAdd(&ls2[t * 16 + m], s2);
            }
        }
    }
    if (STATS) {
        __syncthreads();
        int slot = blockIdx.x & (SLOTS - 1);
        float* sb = sums + (size_t)(b * SLOTS + slot) * 256;
        if (tid < 128) {
            atomicAdd(&sb[tid], ls[tid]);
            atomicAdd(&sb[128 + tid], ls2[tid]);
        }
    }
}

// ---------------- GEMM2 (MFMA): Ybf16[n,64] = BNReLU(h1bf[n,128]) @ W[128,64] ----------------
__global__ __launch_bounds__(256) void gemm2_mfma(const unsigned short* __restrict__ H1,
                                                  const unsigned short* __restrict__ Wp,
                                                  const float* __restrict__ scale,
                                                  const float* __restrict__ shift,
                                                  unsigned short* __restrict__ Y) {
    const int b = blockIdx.y;
    const unsigned short* __restrict__ X = H1 + (size_t)b * NN * 128;
    const unsigned short* __restrict__ W = Wp + (size_t)b * 128 * 64;
    const float* sc = scale + b * 128;
    const float* sh = shift + b * 128;
    unsigned short* __restrict__ Yb = Y + (size_t)b * NN * 64;
    const int tid = threadIdx.x;
    const int w = tid >> 6, lane = tid & 63;
    const int chunk = blockIdx.x * 4 + w;
    if (chunk >= NCHUNK) return;
    const int m = lane & 15, quad = lane >> 4;
    const int row = chunk * 16 + m;

    f32x4 acc[4];
#pragma unroll
    for (int t = 0; t < 4; ++t) acc[t] = (f32x4){0.f, 0.f, 0.f, 0.f};
#pragma unroll
    for (int h = 0; h < 4; ++h) {
        const int k0 = h * 32 + quad * 8;
        bf8 araw = *(const bf8*)&X[(size_t)row * 128 + k0];
        float4 sc0 = *(const float4*)&sc[k0];
        float4 sc1 = *(const float4*)&sc[k0 + 4];
        float4 sh0 = *(const float4*)&sh[k0];
        float4 sh1 = *(const float4*)&sh[k0 + 4];
        float scv[8] = {sc0.x, sc0.y, sc0.z, sc0.w, sc1.x, sc1.y, sc1.z, sc1.w};
        float shv[8] = {sh0.x, sh0.y, sh0.z, sh0.w, sh1.x, sh1.y, sh1.z, sh1.w};
        bf8 af;
#pragma unroll
        for (int j = 0; j < 8; ++j) {
            float v = bf2f((unsigned short)araw[j]);
            v = fmaxf(fmaf(v, scv[j], shv[j]), 0.f);
            af[j] = (short)f2bf(v);
        }
#pragma unroll
        for (int t = 0; t < 4; ++t) {
            bf8 bf = *(const bf8*)&W[((t * 4 + h) * 64 + lane) * 8];
            acc[t] = __builtin_amdgcn_mfma_f32_16x16x32_bf16(af, bf, acc[t], 0, 0, 0);
        }
    }
    const int rbase = chunk * 16 + quad * 4;
#pragma unroll
    for (int t = 0; t < 4; ++t)
#pragma unroll
        for (int r = 0; r < 4; ++r)
            Yb[(size_t)(rbase + r) * 64 + t * 16 + m] = f2bf(acc[t][r]);
}

// ---------------- Batched aggregation (C=64, bf16 in/out), batch-16, scalarized entries ----------------
// Wave per dst node. Entry loads/decodes forced onto SALU via readfirstlane (pk is
// wave-uniform by construction): s_load entry, SGPR weight, scalar row base.
// Remaining VALU per edge: 1 bf16-unpack + 1 fma.
template<bool STATS>
__global__ __launch_bounds__(256) void agg2_kernel(const unsigned short* __restrict__ hall,
                                                   const int* __restrict__ row_ptr,
                                                   const uint32_t* __restrict__ permw,
                                                   const float* __restrict__ dinv,
                                                   unsigned short* __restrict__ out,
                                                   float* __restrict__ sums, int nNodes) {
    const int b = blockIdx.y;
    const unsigned short* __restrict__ h = hall + (size_t)b * NN * 64;
    const int* rp = row_ptr + b * (NN + 1);
    const uint32_t* pe = permw + (size_t)b * NE;
    const float* dv = dinv + (size_t)b * NN;
    unsigned short* ob = out + (size_t)b * nNodes * 64;

    const int wave = blockIdx.x * 4 + (threadIdx.x >> 6);
    const int lane = threadIdx.x & 63;
    float fin = 0.f;
    const bool active = wave < nNodes;
    if (active) {
        const int d = wave;
        const float di = dv[d];
        const int p0 = rp[d], p1 = rp[d + 1];
        float a = 0.f;
        for (int p = p0; p < p1; p += 16) {
            const unsigned short* hp[16];
            float w[16];
#pragma unroll
            for (int k = 0; k < 16; ++k) {
                bool vld = (p + k) < p1;
                int pk = __builtin_amdgcn_readfirstlane(vld ? (p + k) : p0);
                uint32_t en = pe[pk];                          // scalar (s_load)
                int idx = __builtin_amdgcn_readfirstlane((int)(en & 0xFFFFu));
                w[k] = vld ? bf2f((unsigned short)(en >> 16)) : 0.f;  // SGPR
                hp[k] = h + (size_t)idx * 64;                  // scalar base
            }
            float v[16];
#pragma unroll
            for (int k = 0; k < 16; ++k) v[k] = bf2f(hp[k][lane]);  // saddr + lane off
#pragma unroll
            for (int k = 0; k < 16; ++k) a = fmaf(w[k], v[k], a);
        }
        float hd = bf2f(h[(size_t)d * 64 + lane]);
        fin = di * fmaf(di, hd, a);
        ob[(size_t)d * 64 + lane] = f2bf(fin);
    }
    if constexpr (STATS) {
        __shared__ float ls[256], ls2[256];
        ls[threadIdx.x] = fin;
        ls2[threadIdx.x] = fin * fin;
        __syncthreads();
        if (threadIdx.x < 64) {
            float s  = ls[threadIdx.x] + ls[threadIdx.x + 64] + ls[threadIdx.x + 128] + ls[threadIdx.x + 192];
            float s2 = ls2[threadIdx.x] + ls2[threadIdx.x + 64] + ls2[threadIdx.x + 128] + ls2[threadIdx.x + 192];
            int slot = blockIdx.x & (SLOTS - 1);
            float* sb = sums + ((size_t)(b * SLOTS + slot) * 2) * 64;
            atomicAdd(&sb[threadIdx.x], s);
            atomicAdd(&sb[64 + threadIdx.x], s2);
        }
    }
}

// ---------------- BN finalize (slot-striped sums) ----------------
__global__ void bn_finalize2_kernel(const float* __restrict__ sums, int C, float invN,
                                    const float* __restrict__ g0, const float* __restrict__ g1,
                                    const float* __restrict__ b0, const float* __restrict__ b1,
                                    float* __restrict__ scale, float* __restrict__ shift) {
    int b = blockIdx.y;
    int c = threadIdx.x;
    if (c >= C) return;
    float s = 0.f, s2 = 0.f;
    for (int k = 0; k < SLOTS; ++k) {
        const float* sb = sums + ((size_t)(b * SLOTS + k) * 2) * C;
        s += sb[c];
        s2 += sb[C + c];
    }
    const float* gamma = b ? g1 : g0;
    const float* beta = b ? b1 : b0;
    float m = s * invN;
    float var = s2 * invN - m * m;
    float sc = gamma[c] * rsqrtf(var + 1e-5f);
    scale[b * C + c] = sc;
    shift[b * C + c] = beta[c] - m * sc;
}

__global__ void bn_finalize_kernel(const float* __restrict__ sums, int C, float invN,
                                   const float* __restrict__ gamma, const float* __restrict__ beta,
                                   float* __restrict__ scale, float* __restrict__ shift) {
    int c = blockIdx.x * blockDim.x + threadIdx.x;
    if (c >= C) return;
    float m = sums[c] * invN;
    float var = sums[C + c] * invN - m * m;
    float sc = gamma[c] * rsqrtf(var + 1e-5f);
    scale[c] = sc;
    shift[c] = beta[c] - m * sc;
}

// ---------------- Mean pool per graph (bf16 input) ----------------
__global__ __launch_bounds__(64) void pool2_kernel(const unsigned short* __restrict__ x,
                                                   const float* __restrict__ scale,
                                                   const float* __restrict__ shift,
                                                   const int* __restrict__ batch,
                                                   float* __restrict__ Hmean, int n) {
    int b = blockIdx.y;
    const unsigned short* xb = x + (size_t)b * NN * 64;
    int g = blockIdx.x;
    int c = threadIdx.x;
    int lo = 0, hi = n;
    while (lo < hi) { int mid = (lo + hi) >> 1; if (batch[mid] < g) lo = mid + 1; else hi = mid; }
    int start = lo;
    hi = n;
    while (lo < hi) { int mid = (lo + hi) >> 1; if (batch[mid] <= g) lo = mid + 1; else hi = mid; }
    int end = lo;
    float s = 0.f;
    float sc = scale[b * 64 + c], sh = shift[b * 64 + c];
    for (int r = start; r < end; ++r)
        s += fmaxf(fmaf(bf2f(xb[(size_t)r * 64 + c]), sc, sh), 0.f);
    float cf = (float)(end - start);
    Hmean[(size_t)g * 128 + b * 64 + c] = s / fmaxf(cf, 1.f);
}

// ---------------- Head ----------------
__global__ __launch_bounds__(64) void head_gemm1_kernel(const float* __restrict__ H,
                                                        const float* __restrict__ Wf1,
                                                        float* __restrict__ T) {
    __shared__ float row[128];
    int g = blockIdx.x;
    int c = threadIdx.x;
    row[c] = H[(size_t)g * 128 + c];
    row[c + 64] = H[(size_t)g * 128 + 64 + c];
    __syncthreads();
    float acc = 0.f;
#pragma unroll 8
    for (int k = 0; k < 128; ++k) acc = fmaf(row[k], Wf1[k * 64 + c], acc);
    T[(size_t)g * 64 + c] = acc;
}

__global__ __launch_bounds__(64) void head_final_kernel(const float* __restrict__ T,
                                                        const float* __restrict__ scale,
                                                        const float* __restrict__ shift,
                                                        const float* __restrict__ Wf2,
                                                        const float* __restrict__ bf2,
                                                        float* __restrict__ out) {
    int g = blockIdx.x;
    int c = threadIdx.x;
    float v = fmaxf(fmaf(T[(size_t)g * 64 + c], scale[c], shift[c]), 0.f) * Wf2[c];
#pragma unroll
    for (int off = 32; off > 0; off >>= 1) v += __shfl_down(v, off, 64);
    if (c == 0) out[g] = v + bf2[0];
}

template<int C>
__global__ __launch_bounds__(256) void bn_stats_kernel(const float* __restrict__ x, int n,
                                                       float* __restrict__ sums) {
    constexpr int RP = 256 / C;
    __shared__ float ls[256], ls2[256];
    int c = threadIdx.x % C;
    int sub = threadIdx.x / C;
    float s = 0.f, s2 = 0.f;
    for (int r = blockIdx.x * RP + sub; r < n; r += gridDim.x * RP) {
        float v = x[(size_t)r * C + c];
        s += v; s2 += v * v;
    }
    ls[threadIdx.x] = s; ls2[threadIdx.x] = s2;
    __syncthreads();
    if (sub == 0) {
#pragma unroll
        for (int k = 1; k < RP; ++k) { s += ls[k * C + c]; s2 += ls2[k * C + c]; }
        atomicAdd(&sums[c], s);
        atomicAdd(&sums[C + c], s2);
    }
}

// ---------------- Host orchestration ----------------

static inline size_t alignup(size_t x) { return (x + 255) & ~(size_t)255; }

extern "C" void kernel_launch(void* const* d_in, const int* in_sizes, int n_in,
                              void* d_out, int out_size, void* d_ws, size_t ws_size,
                              hipStream_t stream) {
    const float* xc  = (const float*)d_in[0];
    const float* xs  = (const float*)d_in[1];
    const int*   eic = (const int*)d_in[2];
    const int*   eis = (const int*)d_in[3];
    const int*   batch = (const int*)d_in[4];
    const float* W1c = (const float*)d_in[5];
    const float* g1c = (const float*)d_in[7];
    const float* be1c = (const float*)d_in[8];
    const float* W2c = (const float*)d_in[9];
    const float* g2c = (const float*)d_in[11];
    const float* be2c = (const float*)d_in[12];
    const float* W1s = (const float*)d_in[13];
    const float* g1s = (const float*)d_in[15];
    const float* be1s = (const float*)d_in[16];
    const float* W2s = (const float*)d_in[17];
    const float* g2s = (const float*)d_in[19];
    const float* be2s = (const float*)d_in[20];
    const float* Wf1 = (const float*)d_in[21];
    const float* gf1 = (const float*)d_in[23];
    const float* bef1 = (const float*)d_in[24];
    const float* Wf2 = (const float*)d_in[25];
    const float* bf2 = (const float*)d_in[26];
    float* out = (float*)d_out;

    char* ws = (char*)d_ws;
    size_t off = 0;
    auto alloc = [&](size_t bytes) { char* p = ws + off; off += alignup(bytes); return p; };

    int*      bucketCnt = (int*)alloc(2 * NBUCK * 4);
    int*      bucketOff = (int*)alloc(2 * NBUCK * 4);
    int*      bucketCur = (int*)alloc(2 * NBUCK * 4);
    uint32_t* bent      = (uint32_t*)alloc((size_t)2 * NE * 4);   // reused as permw
    uint16_t* perm      = (uint16_t*)alloc(((size_t)2 * NE + 64) * 2);
    int*      row_ptr   = (int*)alloc(2 * (NN + 1) * 4);
    float*    dinv      = (float*)alloc((size_t)2 * NN * 4);
    unsigned short* xbf   = (unsigned short*)alloc((size_t)2 * NN * 64 * 2);
    unsigned short* aggbf = (unsigned short*)alloc((size_t)2 * NN * 64 * 2);
    unsigned short* h1bf  = (unsigned short*)alloc((size_t)2 * NN * 128 * 2);
    unsigned short* h2bf  = (unsigned short*)alloc((size_t)2 * NN * 64 * 2);
    unsigned short* Wp1   = (unsigned short*)alloc((size_t)2 * 64 * 128 * 2);
    unsigned short* Wp2   = (unsigned short*)alloc((size_t)2 * 128 * 64 * 2);
    float*    sums1     = (float*)alloc(((size_t)2 * SLOTS * 256 + (size_t)2 * SLOTS * 128 + 128) * 4);
    float*    sums2     = sums1 + (size_t)2 * SLOTS * 256;
    float*    hsums     = sums2 + (size_t)2 * SLOTS * 128;
    float*    bnscale   = (float*)alloc(2 * 128 * 4);
    float*    bnshift   = (float*)alloc(2 * 128 * 4);
    float*    Hmean     = (float*)alloc((size_t)NG * 128 * 4);
    float*    T         = (float*)alloc((size_t)NG * 64 * 4);

    const float invN = 1.0f / (float)NN;
    const size_t statBytes = ((size_t)2 * SLOTS * 256 + (size_t)2 * SLOTS * 128 + 128) * 4;
    const int gemmBlocks = (NCHUNK + 3) / 4;   // 782
    const int aggBlocks = (NN + 3) / 4;        // 12500

    // ---- conversions / weight packing / stat zeroing ----
    conv_bf16_kernel<<<dim3((NN * 64 / 4 + 255) / 256, 2), 256, 0, stream>>>(xc, xs, xbf);
    pack_w<64, 128><<<dim3(4, 2), 256, 0, stream>>>(W1c, W1s, Wp1);
    pack_w<128, 64><<<dim3(4, 2), 256, 0, stream>>>(W2c, W2s, Wp2);
    hipMemsetAsync(sums1, 0, statBytes, stream);

    // ---- Bucketed CSR build ----
    hipMemsetAsync(bucketCnt, 0, 2 * NBUCK * 4, stream);
    bucket_hist<<<dim3(64, 2), 256, 0, stream>>>(eic + NE, eis + NE, bucketCnt, NE);
    bucket_scan<<<1, 64, 0, stream>>>(bucketCnt, bucketOff, bucketCur);
    bucket_scatter<<<dim3((NE + 2047) / 2048, 2), 256, 0, stream>>>(
        eic, eic + NE, eis, eis + NE, bucketCur, bent, NE);
    csr_build<<<dim3(NBUCK, 2), 256, 0, stream>>>(bent, bucketOff, bucketCnt,
                                                  row_ptr, dinv, perm);
    weight_fill<<<dim3((NE / 4 + 255) / 256, 2), 256, 0, stream>>>(perm, dinv, bent, NE);

    // ---- Layer 1: aggregate bf16 x -> bf16, MFMA GEMM 64->128 with fused BN stats ----
    agg2_kernel<false><<<dim3(aggBlocks, 2), 256, 0, stream>>>(
        xbf, row_ptr, bent, dinv, aggbf, nullptr, NN);
    gemm1_mfma<true><<<dim3(gemmBlocks, 2), 256, 0, stream>>>(aggbf, Wp1, h1bf, sums1);
    bn_finalize2_kernel<<<dim3(1, 2), 128, 0, stream>>>(sums1, 128, invN,
                                                        g1c, g1s, be1c, be1s, bnscale, bnshift);

    // ---- Layer 2: MFMA GEMM 128->64 (BN+ReLU in-register), then aggregate (stats fused) ----
    gemm2_mfma<<<dim3(gemmBlocks, 2), 256, 0, stream>>>(h1bf, Wp2, bnscale, bnshift, h2bf);
    agg2_kernel<true><<<dim3(aggBlocks, 2), 256, 0, stream>>>(
        h2bf, row_ptr, bent, dinv, aggbf, sums2, NN);
    bn_finalize2_kernel<<<dim3(1, 2), 64, 0, stream>>>(sums2, 64, invN,
                                                       g2c, g2s, be2c, be2s, bnscale, bnshift);

    // ---- Pool (BN+ReLU fused, bf16 input) ----
    pool2_kernel<<<dim3(NG, 2), 64, 0, stream>>>(aggbf, bnscale, bnshift, batch, Hmean, NN);

    // ---- Head ----
    head_gemm1_kernel<<<NG, 64, 0, stream>>>(Hmean, Wf1, T);
    bn_stats_kernel<64><<<32, 256, 0, stream>>>(T, NG, hsums);
    bn_finalize_kernel<<<1, 64, 0, stream>>>(hsums, 64, 1.0f / (float)NG, gf1, bef1,
                                             bnscale, bnshift);
    head_final_kernel<<<NG, 64, 0, stream>>>(T, bnscale, bnshift, Wf2, bf2, out);
}

// Round 18
// 387.920 us; speedup vs baseline: 1.0162x; 1.0162x over previous
//
#include <hip/hip_runtime.h>
#include <hip/hip_bf16.h>
#include <cstdint>
#include <cstddef>

#define NN 50000
#define NE 600000
#define NG 2000
#define NBUCK 49          // ceil(50000 / 1024)
#define SLOTS 16
#define NCHUNK 3125       // 50000 / 16 exactly

typedef __attribute__((ext_vector_type(8))) short bf8;
typedef __attribute__((ext_vector_type(4))) float f32x4;

__device__ __forceinline__ unsigned short f2bf(float f) {
    uint32_t u = __float_as_uint(f);
    uint32_t r = (u + 0x7FFFu + ((u >> 16) & 1u)) >> 16;
    return (unsigned short)r;
}
__device__ __forceinline__ float bf2f(unsigned short h) {
    return __uint_as_float(((uint32_t)h) << 16);
}

// ---------------- fp32 -> bf16 conversion (x inputs) ----------------
__global__ __launch_bounds__(256) void conv_bf16_kernel(const float* __restrict__ x0,
                                                        const float* __restrict__ x1,
                                                        unsigned short* __restrict__ out) {
    int b = blockIdx.y;
    const float* x = b ? x1 : x0;
    unsigned short* o = out + (size_t)b * NN * 64;
    int i = (blockIdx.x * 256 + threadIdx.x) * 4;
    if (i + 3 < NN * 64) {
        float4 v = *(const float4*)&x[i];
        ushort4 r = make_ushort4(f2bf(v.x), f2bf(v.y), f2bf(v.z), f2bf(v.w));
        *(ushort4*)&o[i] = r;
    }
}

// ---------------- W pack: [K][N] fp32 -> MFMA B-frag-contiguous bf16 ----------------
template<int K, int N>
__global__ __launch_bounds__(256) void pack_w(const float* __restrict__ W0,
                                              const float* __restrict__ W1,
                                              unsigned short* __restrict__ out) {
    int b = blockIdx.y;
    const float* W = b ? W1 : W0;
    unsigned short* o = out + (size_t)b * K * N;
    int idx = blockIdx.x * 256 + threadIdx.x;
    const int total = (N / 16) * (K / 32) * 64;
    if (idx >= total) return;
    int l = idx & 63;
    int th = idx >> 6;
    int h = th % (K / 32);
    int t = th / (K / 32);
    int col = t * 16 + (l & 15);
    int k0 = h * 32 + (l >> 4) * 8;
    ushort4 lo = make_ushort4(f2bf(W[(k0 + 0) * N + col]), f2bf(W[(k0 + 1) * N + col]),
                              f2bf(W[(k0 + 2) * N + col]), f2bf(W[(k0 + 3) * N + col]));
    ushort4 hi = make_ushort4(f2bf(W[(k0 + 4) * N + col]), f2bf(W[(k0 + 5) * N + col]),
                              f2bf(W[(k0 + 6) * N + col]), f2bf(W[(k0 + 7) * N + col]));
    *(ushort4*)&o[idx * 8] = lo;
    *(ushort4*)&o[idx * 8 + 4] = hi;
}

// ---------------- Bucketed CSR build ----------------
__global__ __launch_bounds__(256) void bucket_hist(const int* __restrict__ d0,
                                                   const int* __restrict__ d1,
                                                   int* __restrict__ bucketCnt, int nE) {
    int b = blockIdx.y;
    const int* dst = b ? d1 : d0;
    __shared__ int h[NBUCK];
    for (int i = threadIdx.x; i < NBUCK; i += 256) h[i] = 0;
    __syncthreads();
    for (int e = blockIdx.x * 256 + threadIdx.x; e < nE; e += gridDim.x * 256)
        atomicAdd(&h[dst[e] >> 10], 1);
    __syncthreads();
    for (int i = threadIdx.x; i < NBUCK; i += 256)
        if (h[i]) atomicAdd(&bucketCnt[b * NBUCK + i], h[i]);
}

__global__ void bucket_scan(const int* __restrict__ bucketCnt,
                            int* __restrict__ bucketOff, int* __restrict__ bucketCur) {
    int b = threadIdx.x;
    if (b < 2) {
        int run = 0;
        for (int i = 0; i < NBUCK; ++i) {
            bucketOff[b * NBUCK + i] = run;
            bucketCur[b * NBUCK + i] = run;
            run += bucketCnt[b * NBUCK + i];
        }
    }
}

__global__ __launch_bounds__(256) void bucket_scatter(const int* __restrict__ s0,
                                                      const int* __restrict__ d0,
                                                      const int* __restrict__ s1,
                                                      const int* __restrict__ d1,
                                                      int* __restrict__ bucketCur,
                                                      uint32_t* __restrict__ bent, int nE) {
    int b = blockIdx.y;
    const int* src = b ? s1 : s0;
    const int* dst = b ? d1 : d0;
    __shared__ int cnt[NBUCK];
    __shared__ int base[NBUCK];
    const int tid = threadIdx.x;
    for (int i = tid; i < NBUCK; i += 256) cnt[i] = 0;
    __syncthreads();

    const int e0 = blockIdx.x * 2048 + tid;
    int bk[8], slot[8];
    uint32_t pay[8];
#pragma unroll
    for (int k = 0; k < 8; ++k) {
        int e = e0 + k * 256;
        if (e < nE) {
            int d = dst[e], s = src[e];
            bk[k] = d >> 10;
            pay[k] = ((uint32_t)(d & 1023) << 16) | (uint32_t)s;
            slot[k] = atomicAdd(&cnt[bk[k]], 1);
        } else bk[k] = -1;
    }
    __syncthreads();
    for (int i = tid; i < NBUCK; i += 256) {
        int c = cnt[i];
        base[i] = c ? atomicAdd(&bucketCur[b * NBUCK + i], c) : 0;
    }
    __syncthreads();
#pragma unroll
    for (int k = 0; k < 8; ++k)
        if (bk[k] >= 0)
            bent[(size_t)b * NE + base[bk[k]] + slot[k]] = pay[k];
}

__global__ __launch_bounds__(256) void csr_build(const uint32_t* __restrict__ bent,
                                                 const int* __restrict__ bucketOff,
                                                 const int* __restrict__ bucketCnt,
                                                 int* __restrict__ row_ptr,
                                                 float* __restrict__ dinv,
                                                 uint16_t* __restrict__ perm) {
    __shared__ int lcnt[1024];
    __shared__ int lcur[1024];
    __shared__ int sscan[256];
    const int bk = blockIdx.x;
    const int b = blockIdx.y;
    const int tid = threadIdx.x;
    const int ebase = bucketOff[b * NBUCK + bk];
    const int ecnt = bucketCnt[b * NBUCK + bk];
    const int node0 = bk << 10;
    const uint32_t* be = bent + (size_t)b * NE + ebase;
    int* rp = row_ptr + b * (NN + 1);
    float* dv = dinv + (size_t)b * NN;
    uint16_t* pm = perm + (size_t)b * NE + ebase;

    for (int i = tid; i < 1024; i += 256) lcnt[i] = 0;
    __syncthreads();
    for (int i = tid; i < ecnt; i += 256) atomicAdd(&lcnt[be[i] >> 16], 1);
    __syncthreads();

    int c[4], s = 0;
#pragma unroll
    for (int j = 0; j < 4; ++j) { c[j] = lcnt[tid * 4 + j]; s += c[j]; }
    sscan[tid] = s;
    __syncthreads();
    for (int off = 1; off < 256; off <<= 1) {
        int v = (tid >= off) ? sscan[tid - off] : 0;
        __syncthreads();
        sscan[tid] += v;
        __syncthreads();
    }
    int run = sscan[tid] - s;
#pragma unroll
    for (int j = 0; j < 4; ++j) {
        int nl = tid * 4 + j;
        int g = node0 + nl;
        if (g < NN) {
            rp[g] = ebase + run;
            lcur[nl] = run;
            dv[g] = rsqrtf((float)c[j] + 1.0f);
        }
        run += c[j];
    }
    if (bk == NBUCK - 1 && tid == 0) rp[NN] = ebase + ecnt;
    __syncthreads();

    for (int i = tid; i < ecnt; i += 256) {
        uint32_t en = be[i];
        int nl = en >> 16;
        int pos = atomicAdd(&lcur[nl], 1);
        pm[pos] = (uint16_t)(en & 0xFFFFu);
    }
}

__global__ __launch_bounds__(256) void weight_fill(const uint16_t* __restrict__ perm,
                                                   const float* __restrict__ dinv,
                                                   uint32_t* __restrict__ permw, int nE) {
    int b = blockIdx.y;
    const uint16_t* pm = perm + (size_t)b * NE;
    const float* dv = dinv + (size_t)b * NN;
    uint32_t* pw = permw + (size_t)b * NE;
    int i = (blockIdx.x * 256 + threadIdx.x) * 4;
    if (i + 3 < nE) {
        ushort4 s4 = *(const ushort4*)&pm[i];
        uint4 o;
        o.x = ((uint32_t)f2bf(dv[s4.x]) << 16) | (uint32_t)s4.x;
        o.y = ((uint32_t)f2bf(dv[s4.y]) << 16) | (uint32_t)s4.y;
        o.z = ((uint32_t)f2bf(dv[s4.z]) << 16) | (uint32_t)s4.z;
        o.w = ((uint32_t)f2bf(dv[s4.w]) << 16) | (uint32_t)s4.w;
        *(uint4*)&pw[i] = o;
    } else {
        for (; i < nE; ++i) {
            uint16_t s = pm[i];
            pw[i] = ((uint32_t)f2bf(dv[s]) << 16) | (uint32_t)s;
        }
    }
}

// ---------------- GEMM1 (MFMA): Ybf16[n,128] = Xbf16[n,64] @ W[64,128] ----------------
template<bool STATS>
__global__ __launch_bounds__(256) void gemm1_mfma(const unsigned short* __restrict__ Xbf,
                                                  const unsigned short* __restrict__ Wp,
                                                  unsigned short* __restrict__ Y,
                                                  float* __restrict__ sums) {
    __shared__ float ls[128], ls2[128];
    const int b = blockIdx.y;
    const unsigned short* __restrict__ X = Xbf + (size_t)b * NN * 64;
    const unsigned short* __restrict__ W = Wp + (size_t)b * 64 * 128;
    unsigned short* __restrict__ Yb = Y + (size_t)b * NN * 128;
    const int tid = threadIdx.x;
    const int w = tid >> 6, lane = tid & 63;
    if (STATS) {
        for (int i = tid; i < 128; i += 256) { ls[i] = 0.f; ls2[i] = 0.f; }
        __syncthreads();
    }
    const int chunk = blockIdx.x * 4 + w;
    const bool act = chunk < NCHUNK;
    const int m = lane & 15, quad = lane >> 4;

    if (act) {
        const int row = chunk * 16 + m;
        bf8 a0 = *(const bf8*)&X[(size_t)row * 64 + quad * 8];
        bf8 a1 = *(const bf8*)&X[(size_t)row * 64 + 32 + quad * 8];
        f32x4 acc[8];
#pragma unroll
        for (int t = 0; t < 8; ++t) acc[t] = (f32x4){0.f, 0.f, 0.f, 0.f};
#pragma unroll
        for (int t = 0; t < 8; ++t) {
            bf8 b0 = *(const bf8*)&W[((t * 2 + 0) * 64 + lane) * 8];
            bf8 b1 = *(const bf8*)&W[((t * 2 + 1) * 64 + lane) * 8];
            acc[t] = __builtin_amdgcn_mfma_f32_16x16x32_bf16(a0, b0, acc[t], 0, 0, 0);
            acc[t] = __builtin_amdgcn_mfma_f32_16x16x32_bf16(a1, b1, acc[t], 0, 0, 0);
        }
        const int rbase = chunk * 16 + quad * 4;
#pragma unroll
        for (int t = 0; t < 8; ++t) {
            float s = 0.f, s2 = 0.f;
#pragma unroll
            for (int r = 0; r < 4; ++r) {
                float v = acc[t][r];
                Yb[(size_t)(rbase + r) * 128 + t * 16 + m] = f2bf(v);
                s += v; s2 = fmaf(v, v, s2);
            }
            if (STATS) {
                atomicAdd(&ls[t * 16 + m], s);
                atomicAdd(&ls2[t * 16 + m], s2);
            }
        }
    }
    if (STATS) {
        __syncthreads();
        int slot = blockIdx.x & (SLOTS - 1);
        float* sb = sums + (size_t)(b * SLOTS + slot) * 256;
        if (tid < 128) {
            atomicAdd(&sb[tid], ls[tid]);
            atomicAdd(&sb[128 + tid], ls2[tid]);
        }
    }
}

// ---------------- GEMM2 (MFMA): Ybf16[n,64] = BNReLU(h1bf[n,128]) @ W[128,64] ----------------
__global__ __launch_bounds__(256) void gemm2_mfma(const unsigned short* __restrict__ H1,
                                                  const unsigned short* __restrict__ Wp,
                                                  const float* __restrict__ scale,
                                                  const float* __restrict__ shift,
                                                  unsigned short* __restrict__ Y) {
    const int b = blockIdx.y;
    const unsigned short* __restrict__ X = H1 + (size_t)b * NN * 128;
    const unsigned short* __restrict__ W = Wp + (size_t)b * 128 * 64;
    const float* sc = scale + b * 128;
    const float* sh = shift + b * 128;
    unsigned short* __restrict__ Yb = Y + (size_t)b * NN * 64;
    const int tid = threadIdx.x;
    const int w = tid >> 6, lane = tid & 63;
    const int chunk = blockIdx.x * 4 + w;
    if (chunk >= NCHUNK) return;
    const int m = lane & 15, quad = lane >> 4;
    const int row = chunk * 16 + m;

    f32x4 acc[4];
#pragma unroll
    for (int t = 0; t < 4; ++t) acc[t] = (f32x4){0.f, 0.f, 0.f, 0.f};
#pragma unroll
    for (int h = 0; h < 4; ++h) {
        const int k0 = h * 32 + quad * 8;
        bf8 araw = *(const bf8*)&X[(size_t)row * 128 + k0];
        float4 sc0 = *(const float4*)&sc[k0];
        float4 sc1 = *(const float4*)&sc[k0 + 4];
        float4 sh0 = *(const float4*)&sh[k0];
        float4 sh1 = *(const float4*)&sh[k0 + 4];
        float scv[8] = {sc0.x, sc0.y, sc0.z, sc0.w, sc1.x, sc1.y, sc1.z, sc1.w};
        float shv[8] = {sh0.x, sh0.y, sh0.z, sh0.w, sh1.x, sh1.y, sh1.z, sh1.w};
        bf8 af;
#pragma unroll
        for (int j = 0; j < 8; ++j) {
            float v = bf2f((unsigned short)araw[j]);
            v = fmaxf(fmaf(v, scv[j], shv[j]), 0.f);
            af[j] = (short)f2bf(v);
        }
#pragma unroll
        for (int t = 0; t < 4; ++t) {
            bf8 bf = *(const bf8*)&W[((t * 4 + h) * 64 + lane) * 8];
            acc[t] = __builtin_amdgcn_mfma_f32_16x16x32_bf16(af, bf, acc[t], 0, 0, 0);
        }
    }
    const int rbase = chunk * 16 + quad * 4;
#pragma unroll
    for (int t = 0; t < 4; ++t)
#pragma unroll
        for (int r = 0; r < 4; ++r)
            Yb[(size_t)(rbase + r) * 64 + t * 16 + m] = f2bf(acc[t][r]);
}

// ---------------- Batched aggregation (C=64, bf16 in/out), batch-16 edges ----------------
// Wave per dst node; one uniform-base row load per edge (proven-best shape).
// Batch 16: mean degree 12 -> ~90% of nodes issue all edges in ONE latency batch.
template<bool STATS>
__global__ __launch_bounds__(256) void agg2_kernel(const unsigned short* __restrict__ hall,
                                                   const int* __restrict__ row_ptr,
                                                   const uint32_t* __restrict__ permw,
                                                   const float* __restrict__ dinv,
                                                   unsigned short* __restrict__ out,
                                                   float* __restrict__ sums, int nNodes) {
    const int b = blockIdx.y;
    const unsigned short* __restrict__ h = hall + (size_t)b * NN * 64;
    const int* rp = row_ptr + b * (NN + 1);
    const uint32_t* pe = permw + (size_t)b * NE;
    const float* dv = dinv + (size_t)b * NN;
    unsigned short* ob = out + (size_t)b * nNodes * 64;

    const int wave = blockIdx.x * 4 + (threadIdx.x >> 6);
    const int lane = threadIdx.x & 63;
    float fin = 0.f;
    const bool active = wave < nNodes;
    if (active) {
        const int d = wave;
        const float di = dv[d];
        const int p0 = rp[d], p1 = rp[d + 1];
        float a = 0.f;
        for (int p = p0; p < p1; p += 16) {
            int idx[16]; float w[16];
#pragma unroll
            for (int k = 0; k < 16; ++k) {
                bool vld = (p + k) < p1;
                int pk = vld ? (p + k) : p;   // dup of first slot: same line, w=0
                uint32_t en = pe[pk];
                idx[k] = (int)(en & 0xFFFFu);
                w[k] = vld ? bf2f((unsigned short)(en >> 16)) : 0.f;
            }
            float v[16];
#pragma unroll
            for (int k = 0; k < 16; ++k) v[k] = bf2f(h[(size_t)idx[k] * 64 + lane]);
#pragma unroll
            for (int k = 0; k < 16; ++k) a = fmaf(w[k], v[k], a);
        }
        float hd = bf2f(h[(size_t)d * 64 + lane]);
        fin = di * fmaf(di, hd, a);
        ob[(size_t)d * 64 + lane] = f2bf(fin);
    }
    if constexpr (STATS) {
        __shared__ float ls[256], ls2[256];
        ls[threadIdx.x] = fin;
        ls2[threadIdx.x] = fin * fin;
        __syncthreads();
        if (threadIdx.x < 64) {
            float s  = ls[threadIdx.x] + ls[threadIdx.x + 64] + ls[threadIdx.x + 128] + ls[threadIdx.x + 192];
            float s2 = ls2[threadIdx.x] + ls2[threadIdx.x + 64] + ls2[threadIdx.x + 128] + ls2[threadIdx.x + 192];
            int slot = blockIdx.x & (SLOTS - 1);
            float* sb = sums + ((size_t)(b * SLOTS + slot) * 2) * 64;
            atomicAdd(&sb[threadIdx.x], s);
            atomicAdd(&sb[64 + threadIdx.x], s2);
        }
    }
}

// ---------------- BN finalize (slot-striped sums) ----------------
__global__ void bn_finalize2_kernel(const float* __restrict__ sums, int C, float invN,
                                    const float* __restrict__ g0, const float* __restrict__ g1,
                                    const float* __restrict__ b0, const float* __restrict__ b1,
                                    float* __restrict__ scale, float* __restrict__ shift) {
    int b = blockIdx.y;
    int c = threadIdx.x;
    if (c >= C) return;
    float s = 0.f, s2 = 0.f;
    for (int k = 0; k < SLOTS; ++k) {
        const float* sb = sums + ((size_t)(b * SLOTS + k) * 2) * C;
        s += sb[c];
        s2 += sb[C + c];
    }
    const float* gamma = b ? g1 : g0;
    const float* beta = b ? b1 : b0;
    float m = s * invN;
    float var = s2 * invN - m * m;
    float sc = gamma[c] * rsqrtf(var + 1e-5f);
    scale[b * C + c] = sc;
    shift[b * C + c] = beta[c] - m * sc;
}

__global__ void bn_finalize_kernel(const float* __restrict__ sums, int C, float invN,
                                   const float* __restrict__ gamma, const float* __restrict__ beta,
                                   float* __restrict__ scale, float* __restrict__ shift) {
    int c = blockIdx.x * blockDim.x + threadIdx.x;
    if (c >= C) return;
    float m = sums[c] * invN;
    float var = sums[C + c] * invN - m * m;
    float sc = gamma[c] * rsqrtf(var + 1e-5f);
    scale[c] = sc;
    shift[c] = beta[c] - m * sc;
}

// ---------------- Mean pool per graph (bf16 input) ----------------
__global__ __launch_bounds__(64) void pool2_kernel(const unsigned short* __restrict__ x,
                                                   const float* __restrict__ scale,
                                                   const float* __restrict__ shift,
                                                   const int* __restrict__ batch,
                                                   float* __restrict__ Hmean, int n) {
    int b = blockIdx.y;
    const unsigned short* xb = x + (size_t)b * NN * 64;
    int g = blockIdx.x;
    int c = threadIdx.x;
    int lo = 0, hi = n;
    while (lo < hi) { int mid = (lo + hi) >> 1; if (batch[mid] < g) lo = mid + 1; else hi = mid; }
    int start = lo;
    hi = n;
    while (lo < hi) { int mid = (lo + hi) >> 1; if (batch[mid] <= g) lo = mid + 1; else hi = mid; }
    int end = lo;
    float s = 0.f;
    float sc = scale[b * 64 + c], sh = shift[b * 64 + c];
    for (int r = start; r < end; ++r)
        s += fmaxf(fmaf(bf2f(xb[(size_t)r * 64 + c]), sc, sh), 0.f);
    float cf = (float)(end - start);
    Hmean[(size_t)g * 128 + b * 64 + c] = s / fmaxf(cf, 1.f);
}

// ---------------- Head ----------------
__global__ __launch_bounds__(64) void head_gemm1_kernel(const float* __restrict__ H,
                                                        const float* __restrict__ Wf1,
                                                        float* __restrict__ T) {
    __shared__ float row[128];
    int g = blockIdx.x;
    int c = threadIdx.x;
    row[c] = H[(size_t)g * 128 + c];
    row[c + 64] = H[(size_t)g * 128 + 64 + c];
    __syncthreads();
    float acc = 0.f;
#pragma unroll 8
    for (int k = 0; k < 128; ++k) acc = fmaf(row[k], Wf1[k * 64 + c], acc);
    T[(size_t)g * 64 + c] = acc;
}

__global__ __launch_bounds__(64) void head_final_kernel(const float* __restrict__ T,
                                                        const float* __restrict__ scale,
                                                        const float* __restrict__ shift,
                                                        const float* __restrict__ Wf2,
                                                        const float* __restrict__ bf2,
                                                        float* __restrict__ out) {
    int g = blockIdx.x;
    int c = threadIdx.x;
    float v = fmaxf(fmaf(T[(size_t)g * 64 + c], scale[c], shift[c]), 0.f) * Wf2[c];
#pragma unroll
    for (int off = 32; off > 0; off >>= 1) v += __shfl_down(v, off, 64);
    if (c == 0) out[g] = v + bf2[0];
}

template<int C>
__global__ __launch_bounds__(256) void bn_stats_kernel(const float* __restrict__ x, int n,
                                                       float* __restrict__ sums) {
    constexpr int RP = 256 / C;
    __shared__ float ls[256], ls2[256];
    int c = threadIdx.x % C;
    int sub = threadIdx.x / C;
    float s = 0.f, s2 = 0.f;
    for (int r = blockIdx.x * RP + sub; r < n; r += gridDim.x * RP) {
        float v = x[(size_t)r * C + c];
        s += v; s2 += v * v;
    }
    ls[threadIdx.x] = s; ls2[threadIdx.x] = s2;
    __syncthreads();
    if (sub == 0) {
#pragma unroll
        for (int k = 1; k < RP; ++k) { s += ls[k * C + c]; s2 += ls2[k * C + c]; }
        atomicAdd(&sums[c], s);
        atomicAdd(&sums[C + c], s2);
    }
}

// ---------------- Host orchestration ----------------

static inline size_t alignup(size_t x) { return (x + 255) & ~(size_t)255; }

extern "C" void kernel_launch(void* const* d_in, const int* in_sizes, int n_in,
                              void* d_out, int out_size, void* d_ws, size_t ws_size,
                              hipStream_t stream) {
    const float* xc  = (const float*)d_in[0];
    const float* xs  = (const float*)d_in[1];
    const int*   eic = (const int*)d_in[2];
    const int*   eis = (const int*)d_in[3];
    const int*   batch = (const int*)d_in[4];
    const float* W1c = (const float*)d_in[5];
    const float* g1c = (const float*)d_in[7];
    const float* be1c = (const float*)d_in[8];
    const float* W2c = (const float*)d_in[9];
    const float* g2c = (const float*)d_in[11];
    const float* be2c = (const float*)d_in[12];
    const float* W1s = (const float*)d_in[13];
    const float* g1s = (const float*)d_in[15];
    const float* be1s = (const float*)d_in[16];
    const float* W2s = (const float*)d_in[17];
    const float* g2s = (const float*)d_in[19];
    const float* be2s = (const float*)d_in[20];
    const float* Wf1 = (const float*)d_in[21];
    const float* gf1 = (const float*)d_in[23];
    const float* bef1 = (const float*)d_in[24];
    const float* Wf2 = (const float*)d_in[25];
    const float* bf2 = (const float*)d_in[26];
    float* out = (float*)d_out;

    char* ws = (char*)d_ws;
    size_t off = 0;
    auto alloc = [&](size_t bytes) { char* p = ws + off; off += alignup(bytes); return p; };

    int*      bucketCnt = (int*)alloc(2 * NBUCK * 4);
    int*      bucketOff = (int*)alloc(2 * NBUCK * 4);
    int*      bucketCur = (int*)alloc(2 * NBUCK * 4);
    uint32_t* bent      = (uint32_t*)alloc((size_t)2 * NE * 4);   // reused as permw
    uint16_t* perm      = (uint16_t*)alloc(((size_t)2 * NE + 64) * 2);
    int*      row_ptr   = (int*)alloc(2 * (NN + 1) * 4);
    float*    dinv      = (float*)alloc((size_t)2 * NN * 4);
    unsigned short* xbf   = (unsigned short*)alloc((size_t)2 * NN * 64 * 2);
    unsigned short* aggbf = (unsigned short*)alloc((size_t)2 * NN * 64 * 2);
    unsigned short* h1bf  = (unsigned short*)alloc((size_t)2 * NN * 128 * 2);
    unsigned short* h2bf  = (unsigned short*)alloc((size_t)2 * NN * 64 * 2);
    unsigned short* Wp1   = (unsigned short*)alloc((size_t)2 * 64 * 128 * 2);
    unsigned short* Wp2   = (unsigned short*)alloc((size_t)2 * 128 * 64 * 2);
    float*    sums1     = (float*)alloc(((size_t)2 * SLOTS * 256 + (size_t)2 * SLOTS * 128 + 128) * 4);
    float*    sums2     = sums1 + (size_t)2 * SLOTS * 256;
    float*    hsums     = sums2 + (size_t)2 * SLOTS * 128;
    float*    bnscale   = (float*)alloc(2 * 128 * 4);
    float*    bnshift   = (float*)alloc(2 * 128 * 4);
    float*    Hmean     = (float*)alloc((size_t)NG * 128 * 4);
    float*    T         = (float*)alloc((size_t)NG * 64 * 4);

    const float invN = 1.0f / (float)NN;
    const size_t statBytes = ((size_t)2 * SLOTS * 256 + (size_t)2 * SLOTS * 128 + 128) * 4;
    const int gemmBlocks = (NCHUNK + 3) / 4;   // 782
    const int aggBlocks = (NN + 3) / 4;        // 12500

    // ---- conversions / weight packing / stat zeroing ----
    conv_bf16_kernel<<<dim3((NN * 64 / 4 + 255) / 256, 2), 256, 0, stream>>>(xc, xs, xbf);
    pack_w<64, 128><<<dim3(4, 2), 256, 0, stream>>>(W1c, W1s, Wp1);
    pack_w<128, 64><<<dim3(4, 2), 256, 0, stream>>>(W2c, W2s, Wp2);
    hipMemsetAsync(sums1, 0, statBytes, stream);

    // ---- Bucketed CSR build ----
    hipMemsetAsync(bucketCnt, 0, 2 * NBUCK * 4, stream);
    bucket_hist<<<dim3(64, 2), 256, 0, stream>>>(eic + NE, eis + NE, bucketCnt, NE);
    bucket_scan<<<1, 64, 0, stream>>>(bucketCnt, bucketOff, bucketCur);
    bucket_scatter<<<dim3((NE + 2047) / 2048, 2), 256, 0, stream>>>(
        eic, eic + NE, eis, eis + NE, bucketCur, bent, NE);
    csr_build<<<dim3(NBUCK, 2), 256, 0, stream>>>(bent, bucketOff, bucketCnt,
                                                  row_ptr, dinv, perm);
    weight_fill<<<dim3((NE / 4 + 255) / 256, 2), 256, 0, stream>>>(perm, dinv, bent, NE);

    // ---- Layer 1: aggregate bf16 x -> bf16, MFMA GEMM 64->128 with fused BN stats ----
    agg2_kernel<false><<<dim3(aggBlocks, 2), 256, 0, stream>>>(
        xbf, row_ptr, bent, dinv, aggbf, nullptr, NN);
    gemm1_mfma<true><<<dim3(gemmBlocks, 2), 256, 0, stream>>>(aggbf, Wp1, h1bf, sums1);
    bn_finalize2_kernel<<<dim3(1, 2), 128, 0, stream>>>(sums1, 128, invN,
                                                        g1c, g1s, be1c, be1s, bnscale, bnshift);

    // ---- Layer 2: MFMA GEMM 128->64 (BN+ReLU in-register), then aggregate (stats fused) ----
    gemm2_mfma<<<dim3(gemmBlocks, 2), 256, 0, stream>>>(h1bf, Wp2, bnscale, bnshift, h2bf);
    agg2_kernel<true><<<dim3(aggBlocks, 2), 256, 0, stream>>>(
        h2bf, row_ptr, bent, dinv, aggbf, sums2, NN);
    bn_finalize2_kernel<<<dim3(1, 2), 64, 0, stream>>>(sums2, 64, invN,
                                                       g2c, g2s, be2c, be2s, bnscale, bnshift);

    // ---- Pool (BN+ReLU fused, bf16 input) ----
    pool2_kernel<<<dim3(NG, 2), 64, 0, stream>>>(aggbf, bnscale, bnshift, batch, Hmean, NN);

    // ---- Head ----
    head_gemm1_kernel<<<NG, 64, 0, stream>>>(Hmean, Wf1, T);
    bn_stats_kernel<64><<<32, 256, 0, stream>>>(T, NG, hsums);
    bn_finalize_kernel<<<1, 64, 0, stream>>>(hsums, 64, 1.0f / (float)NG, gf1, bef1,
                                             bnscale, bnshift);
    head_final_kernel<<<NG, 64, 0, stream>>>(T, bnscale, bnshift, Wf2, bf2, out);
}